// Round 5
// baseline (249.901 us; speedup 1.0000x reference)
//
#include <hip/hip_runtime.h>

typedef __bf16 bf16x8 __attribute__((ext_vector_type(8)));
typedef float f32x4 __attribute__((ext_vector_type(4)));

#define EPS_F 1e-5f

// direct global -> LDS DMA, 16 B per lane. LDS dest is wave-uniform base +
// lane*16 (m104); global src is per-lane.
__device__ __forceinline__ void gload_lds16(const void* g, void* l) {
    __builtin_amdgcn_global_load_lds(
        (const __attribute__((address_space(1))) unsigned int*)g,
        (__attribute__((address_space(3))) unsigned int*)l, 16, 0, 0);
}

// -------------------------------------------------------------------------
// k_pack: merged pack of x and w1 (round 10: 5 launches -> 3).
//   b < 128 : x[b][c][p] fp32 -> xt[b][kt][p][cc] bf16 (kt=c/32, cc=c%32)
//   b == 128: w1[r][c]  fp32 -> w1t[kt][r][cc] bf16   (32 y-blocks)
// grid (129, 32), block 256.
// -------------------------------------------------------------------------
__global__ __launch_bounds__(256) void k_pack(
    const float* __restrict__ x, const float* __restrict__ w1,
    __bf16* __restrict__ xt, __bf16* __restrict__ w1t)
{
    const int b = blockIdx.x, kt = blockIdx.y, tid = threadIdx.x;
    if (b == 128) {
        // w1 pack: this block covers groups [kt*1024, kt*1024+1024)
#pragma unroll
        for (int j = 0; j < 4; j++) {
            const int it = kt * 1024 + tid + j * 256;
            const int kk = it >> 10, rem = it & 1023, r = rem >> 2, g = rem & 3;
            const float* s = w1 + (size_t)r * 1024 + kk * 32 + g * 8;
            bf16x8 o;
#pragma unroll
            for (int e = 0; e < 8; e++) o[e] = (__bf16)s[e];
            *(bf16x8*)(w1t + (size_t)it * 8) = o;
        }
        return;
    }
    __shared__ float xs[32][204];            // pad 204 (float4-aligned rows)
    const float* src = x + ((size_t)b * 1024 + (size_t)kt * 32) * 196;
#pragma unroll
    for (int k = 0; k < 7; k++) {
        const int i4 = tid + k * 256;
        if (i4 < 1568) {                     // 32 c * 49 float4
            const int c = i4 / 49, pq = i4 % 49;
            const float4 v = *(const float4*)(src + c * 196 + pq * 4);
            *(float4*)&xs[c][pq * 4] = v;
        }
    }
    __syncthreads();
    __bf16* dst = xt + (size_t)(b * 32 + kt) * 196 * 32;
#pragma unroll
    for (int k = 0; k < 4; k++) {
        const int it = tid + k * 256;
        if (it < 784) {                      // 196 p * 4 groups of 8 c
            const int p = it >> 2, g = it & 3;
            bf16x8 o;
#pragma unroll
            for (int j = 0; j < 8; j++) o[j] = (__bf16)xs[g * 8 + j][p];
            *(bf16x8*)(dst + (size_t)p * 32 + g * 8) = o;   // fully contiguous
        }
    }
}

// -------------------------------------------------------------------------
// Kernel 1 (MFMA): pooled_part[mc][b][r] = sum_{p in m-chunk} hswish(BN(x@w1))
// Round 10: 3-deep DMA pipeline. Per-step MFMA work (~160 cyc) << load
// latency (200-900 cyc), so round-9's 1-deep vmcnt(3) stalled every step.
// Now 4 LDS buffers, prefetch 3 ahead, counted vmcnt(6), ONE barrier/step
// (issue-after-barrier makes the WAR on buf (t-1)&3 safe: all waves
// finished step t-1 reads before the barrier; sched_barrier(0) fences
// compiler hoisting across the non-fencing s_barrier).
// grid (128 b, 2 mc), block 512 (8 waves 2m x 4n). LDS 98 KB, 1 block/CU.
// -------------------------------------------------------------------------
__global__ __launch_bounds__(512) void k_gemm_pool(
    const __bf16* __restrict__ xt,       // [b][kt][196][32]
    const __bf16* __restrict__ w1t,      // [kt][256][32]
    const float* __restrict__ g1,
    const float* __restrict__ b1,
    const float* __restrict__ m1,
    const float* __restrict__ v1,
    float* __restrict__ pooled_part)     // [2][128][256]
{
    __shared__ __bf16 Alds[4][4096];     // 128 rows x 32  (8 KB each)
    __shared__ __bf16 Blds[4][8192];     // 256 rows x 32 (16 KB each)
    __shared__ float pool_lds[2][256];

    const int b   = blockIdx.x;
    const int mc  = blockIdx.y;
    const int tid = threadIdx.x;
    const int wave = tid >> 6, lane = tid & 63;
    const int wm = wave >> 2, wn = wave & 3;   // wave grid 2(m) x 4(n)
    const int q  = lane >> 4, ln = lane & 15;
    const int nm = (wm == 0) ? 4 : 3;          // 7 m-tiles split 4 + 3

    f32x4 acc[4][4];
#pragma unroll
    for (int i = 0; i < 4; i++)
#pragma unroll
        for (int j = 0; j < 4; j++) acc[i][j] = (f32x4){0.f, 0.f, 0.f, 0.f};

    // per-lane global srcs (advance by tile stride per kt)
    const __bf16* xa = xt + ((size_t)b * 32 * 196 + (size_t)mc * 112) * 32 + tid * 8;
    const __bf16* wb = w1t + tid * 8;

    auto issue = [&](int kt, int buf) {
        gload_lds16(xa + (size_t)kt * (196 * 32), &Alds[buf][wave * 512]);
        gload_lds16(wb + (size_t)kt * 8192,        &Blds[buf][wave * 512]);
        gload_lds16(wb + (size_t)kt * 8192 + 4096, &Blds[buf][4096 + wave * 512]);
    };

    issue(0, 0); issue(1, 1); issue(2, 2);     // 9 loads in flight

    for (int t = 0; t < 32; ++t) {
        if (t < 30)       asm volatile("s_waitcnt vmcnt(6)" ::: "memory");
        else if (t == 30) asm volatile("s_waitcnt vmcnt(3)" ::: "memory");
        else              asm volatile("s_waitcnt vmcnt(0)" ::: "memory");
        __builtin_amdgcn_s_barrier();            // all waves: tile t landed
        __builtin_amdgcn_sched_barrier(0);       // no memory-op hoisting
        if (t + 3 < 32) issue(t + 3, (t + 3) & 3);   // overwrites buf (t-1)&3
        __builtin_amdgcn_sched_barrier(0);       // ds_reads stay below
        const int cur = t & 3;
        bf16x8 bfr[4];
#pragma unroll
        for (int ni = 0; ni < 4; ni++)
            bfr[ni] = *(const bf16x8*)&Blds[cur][(((wn * 4 + ni) * 16 + ln) * 32) + q * 8];
#pragma unroll
        for (int mi = 0; mi < 4; mi++) {
            if (mi < nm) {
                const bf16x8 af =
                    *(const bf16x8*)&Alds[cur][(((wm * 4 + mi) * 16 + ln) * 32) + q * 8];
#pragma unroll
                for (int ni = 0; ni < 4; ni++)
                    acc[mi][ni] = __builtin_amdgcn_mfma_f32_16x16x32_bf16(
                        af, bfr[ni], acc[mi][ni], 0, 0, 0);
            }
        }
    }

    // ---- epilogue: BN + hardswish + partial pool (mask p >= 196) ----
    float psum[4] = {0.f, 0.f, 0.f, 0.f};
#pragma unroll
    for (int ni = 0; ni < 4; ni++) {
        const int r = (wn * 4 + ni) * 16 + ln;
        const float s1 = g1[r] * rsqrtf(v1[r] + EPS_F);
        const float mu = m1[r];
        const float be = b1[r];
#pragma unroll
        for (int mi = 0; mi < 4; mi++) {
            if (mi < nm) {
#pragma unroll
                for (int i = 0; i < 4; i++) {
                    const int m = mc * 112 + (wm * 4 + mi) * 16 + q * 4 + i;
                    if (m < 196) {
                        float v = acc[mi][ni][i];
                        v = (v - mu) * s1 + be;
                        const float g = fminf(fmaxf(v + 3.f, 0.f), 6.f);
                        psum[ni] += v * g * (1.f / 6.f);
                    }
                }
            }
        }
    }
#pragma unroll
    for (int ni = 0; ni < 4; ni++) {
        psum[ni] += __shfl_xor(psum[ni], 16, 64);
        psum[ni] += __shfl_xor(psum[ni], 32, 64);
    }
    if (lane < 16) {
#pragma unroll
        for (int ni = 0; ni < 4; ni++)
            pool_lds[wm][(wn * 4 + ni) * 16 + lane] = psum[ni];
    }
    __syncthreads();
    if (tid < 256)
        pooled_part[(size_t)mc * (128 * 256) + b * 256 + tid] =
            (pool_lds[0][tid] + pool_lds[1][tid]) * (1.f / 196.f);
}

__device__ __forceinline__ void prep1(float s, float e, int n, int size, int i,
                                      int& lo, int& hi, float& w0, float& w1)
{
    const float bsz = (e - s) / (float)n;
    float c = s + ((float)i + 0.5f) * bsz;
    const float valid = (c >= -1.f && c <= (float)size) ? 1.f : 0.f;
    c = fminf(fmaxf(c, 0.f), (float)(size - 1));
    lo = (int)floorf(c);
    hi = min(lo + 1, size - 1);
    const float f = c - (float)lo;
    w0 = (1.f - f) * valid;
    w1 = f * valid;
}

// -------------------------------------------------------------------------
// Kernel 3 (fused logits+ROI): each block first computes the 6 roi params
// from pooled_part (64 threads, hidden under the x-staging loads), then
// ROI-align as before. grid (128, 32), block 256.
// -------------------------------------------------------------------------
__global__ __launch_bounds__(256) void k_roi(
    const float* __restrict__ x,
    const float* __restrict__ pooled_part,   // [2][128][256]
    const float* __restrict__ w2,
    const float* __restrict__ g2,
    const float* __restrict__ b2,
    const float* __restrict__ m2,
    const float* __restrict__ v2,
    float* __restrict__ out)
{
    __shared__ float xs[32 * 200];   // 32 ch x 196 (pad 200)  25.6 KiB
    __shared__ int   soff[8][80];    // sample flat offsets (po-major)
    __shared__ float swt[8][80];     // sample weights
    __shared__ float roi_s[6];

    const int b = blockIdx.x, c0 = blockIdx.y * 32;
    const int tid = threadIdx.x;

    // ---- stage 32 channels, coalesced float4 (196 = 49*4) ----
    const float* xb = x + ((size_t)b * 1024 + c0) * 196;
#pragma unroll
    for (int k = 0; k < 7; k++) {
        const int i4 = tid + k * 256;
        if (i4 < 1568) {                       // 32*49
            const int c = i4 / 49, pq = i4 % 49;
            const float4 v = *(const float4*)(xb + c * 196 + pq * 4);
            *(float4*)&xs[c * 200 + pq * 4] = v;
        }
    }
    // ---- logits (wave 0), overlapped with staging ----
    if (tid < 64) {
        const float4 pa = ((const float4*)(pooled_part + b * 256))[tid];
        const float4 pb = ((const float4*)(pooled_part + 128 * 256 + b * 256))[tid];
        float4 p4;
        p4.x = pa.x + pb.x; p4.y = pa.y + pb.y;
        p4.z = pa.z + pb.z; p4.w = pa.w + pb.w;
        float part[6];
#pragma unroll
        for (int j = 0; j < 6; j++) {
            const float4 w = *(const float4*)(w2 + j * 256 + tid * 4);
            part[j] = p4.x * w.x + p4.y * w.y + p4.z * w.z + p4.w * w.w;
        }
#pragma unroll
        for (int j = 0; j < 6; j++)
#pragma unroll
            for (int off = 32; off >= 1; off >>= 1)
                part[j] += __shfl_xor(part[j], off, 64);
        if (tid == 0) {
            const float SC[3] = {7.f, 7.f, 4.f};
#pragma unroll
            for (int j = 0; j < 6; j++) {
                float l = part[j];
                const float s = g2[j] * rsqrtf(v2[j] + EPS_F);
                l = (l - m2[j]) * s + b2[j];
                const float raw = 1.f / (1.f + expf(-l));
                roi_s[j] = (j < 3) ? 0.5f * raw * SC[j]
                                   : (1.f - 0.5f * raw) * SC[j - 3];
            }
        }
    }
    __syncthreads();
    // ---- weight/offset tables (75 threads) ----
    if (tid < 75) {
        const int po = tid;
        const int to = po / 25, rem = po % 25, yo = rem / 5, xo = rem % 5;
        int tl, th, yl, yh, xl, xh;
        float tw0, tw1, yw0, yw1, xw0, xw1;
        prep1(roi_s[2], roi_s[5], 3, 4, to, tl, th, tw0, tw1);
        prep1(roi_s[1], roi_s[4], 5, 7, yo, yl, yh, yw0, yw1);
        prep1(roi_s[0], roi_s[3], 5, 7, xo, xl, xh, xw0, xw1);
#pragma unroll
        for (int s = 0; s < 8; s++) {
            const int   ti = (s & 4) ? th : tl;
            const int   yi = (s & 2) ? yh : yl;
            const int   xi = (s & 1) ? xh : xl;
            const float w = ((s & 4) ? tw1 : tw0) *
                            ((s & 2) ? yw1 : yw0) *
                            ((s & 1) ? xw1 : xw0);
            soff[s][po] = ti * 49 + yi * 7 + xi;
            swt[s][po]  = w;
        }
    }
    __syncthreads();

    // ---- compute: 32*75 = 2400 outputs ----
    const size_t obase = ((size_t)b * 1024 + c0) * 75;
#pragma unroll
    for (int k = 0; k < 10; k++) {
        const int e = tid + k * 256;
        if (e < 2400) {
            const int c = e / 75, po = e % 75;
            const float* row = &xs[c * 200];
            float v = 0.f;
#pragma unroll
            for (int s = 0; s < 8; s++)
                v += swt[s][po] * row[soff[s][po]];
            out[obase + e] = v;     // e == c*75+po: fully coalesced
        }
    }
}

extern "C" void kernel_launch(void* const* d_in, const int* in_sizes, int n_in,
                              void* d_out, int out_size, void* d_ws, size_t ws_size,
                              hipStream_t stream)
{
    const float* x  = (const float*)d_in[0];
    const float* w1 = (const float*)d_in[1];
    const float* g1 = (const float*)d_in[2];
    const float* b1 = (const float*)d_in[3];
    const float* m1 = (const float*)d_in[4];
    const float* v1 = (const float*)d_in[5];
    const float* w2 = (const float*)d_in[6];
    const float* g2 = (const float*)d_in[7];
    const float* b2 = (const float*)d_in[8];
    const float* m2 = (const float*)d_in[9];
    const float* v2 = (const float*)d_in[10];

    // workspace layout (bytes):
    //   xt   : 128*32*196*32*2 = 51,380,224  (+8192 OOB pad for last-tile DMA)
    //   w1t  : 32*256*32*2     =    524,288
    //   pooled_part : 2*128*256*4 = 262,144
    char* wsb = (char*)d_ws;
    __bf16* xt     = (__bf16*)wsb;
    __bf16* w1t    = (__bf16*)(wsb + 51388416);
    float*  pooled = (float*)(wsb + 51912704);
    float*  out    = (float*)d_out;

    k_pack<<<dim3(129, 32), 256, 0, stream>>>(x, w1, xt, w1t);
    k_gemm_pool<<<dim3(128, 2), 512, 0, stream>>>(xt, w1t, g1, b1, m1, v1, pooled);
    k_roi<<<dim3(128, 32), 256, 0, stream>>>(x, pooled, w2, g2, b2, m2, v2, out);
}

// Round 6
// 244.207 us; speedup vs baseline: 1.0233x; 1.0233x over previous
//
#include <hip/hip_runtime.h>

typedef __bf16 bf16x8 __attribute__((ext_vector_type(8)));
typedef float f32x4 __attribute__((ext_vector_type(4)));

#define EPS_F 1e-5f

// direct global -> LDS DMA, 16 B per lane. LDS dest is wave-uniform base +
// lane*16 (m104); global src is per-lane.
__device__ __forceinline__ void gload_lds16(const void* g, void* l) {
    __builtin_amdgcn_global_load_lds(
        (const __attribute__((address_space(1))) unsigned int*)g,
        (__attribute__((address_space(3))) unsigned int*)l, 16, 0, 0);
}

// -------------------------------------------------------------------------
// k_pack: merged pack of x and w1.
//   b < 128 : x[b][c][p] fp32 -> xt[b][kt][p][cc] bf16 (kt=c/32, cc=c%32)
//   b == 128: w1[r][c]  fp32 -> w1t[kt][r][cc] bf16   (32 y-blocks)
// grid (129, 32), block 256. xs padded 205: transpose-read c-groups 8 apart
// land on distinct banks (8*205 % 32 = 8) -> conflict-free column reads.
// -------------------------------------------------------------------------
__global__ __launch_bounds__(256) void k_pack(
    const float* __restrict__ x, const float* __restrict__ w1,
    __bf16* __restrict__ xt, __bf16* __restrict__ w1t)
{
    const int b = blockIdx.x, kt = blockIdx.y, tid = threadIdx.x;
    if (b == 128) {
#pragma unroll
        for (int j = 0; j < 4; j++) {
            const int it = kt * 1024 + tid + j * 256;
            const int kk = it >> 10, rem = it & 1023, r = rem >> 2, g = rem & 3;
            const float* s = w1 + (size_t)r * 1024 + kk * 32 + g * 8;
            bf16x8 o;
#pragma unroll
            for (int e = 0; e < 8; e++) o[e] = (__bf16)s[e];
            *(bf16x8*)(w1t + (size_t)it * 8) = o;
        }
        return;
    }
    __shared__ float xs[32][205];
    const float* src = x + ((size_t)b * 1024 + (size_t)kt * 32) * 196;
#pragma unroll
    for (int k = 0; k < 7; k++) {
        const int i4 = tid + k * 256;
        if (i4 < 1568) {                     // 32 c * 49 float4
            const int c = i4 / 49, pq = i4 % 49;
            const float4 v = *(const float4*)(src + c * 196 + pq * 4);
            *(float4*)&xs[c][pq * 4] = v;
        }
    }
    __syncthreads();
    __bf16* dst = xt + (size_t)(b * 32 + kt) * 196 * 32;
#pragma unroll
    for (int k = 0; k < 4; k++) {
        const int it = tid + k * 256;
        if (it < 784) {                      // 196 p * 4 groups of 8 c
            const int p = it >> 2, g = it & 3;
            bf16x8 o;
#pragma unroll
            for (int j = 0; j < 8; j++) o[j] = (__bf16)xs[g * 8 + j][p];
            *(bf16x8*)(dst + (size_t)p * 32 + g * 8) = o;   // fully contiguous
        }
    }
}

// -------------------------------------------------------------------------
// Kernel 1 (MFMA): pooled_part[mc][b][r-slice] partial pool of hswish(BN(x@w1))
// Round 11: round-10's grid (128,2)=256 blocks = 1 block/CU with 98 KB LDS
// -> every barrier bubble idles the whole CU (gemm stuck ~55 us despite a
// 10-25 us demand floor). Now N-split: block = (b, mc, nh) does 112x128,
// grid 512 = 2 co-resident blocks/CU (LDS 65 KB), pipeline 3-ahead depth-4,
// counted vmcnt(4). Block-id decode keeps all 4 blocks of a b on ONE XCD
// (ids differ by 128 = 0 mod 8) -> xt[b] panels are L2-local.
// -------------------------------------------------------------------------
__global__ __launch_bounds__(512) void k_gemm_pool(
    const __bf16* __restrict__ xt,       // [b][kt][196][32]
    const __bf16* __restrict__ w1t,      // [kt][256][32]
    const float* __restrict__ g1,
    const float* __restrict__ b1,
    const float* __restrict__ m1,
    const float* __restrict__ v1,
    float* __restrict__ pooled_part)     // [2][128][256]
{
    __shared__ __bf16 Alds[4][4096];     // 128 rows x 32  (8 KB each)
    __shared__ __bf16 Blds[4][4096];     // 128 rows x 32  (8 KB each)
    __shared__ float pool_lds[2][128];

    const int bid = blockIdx.x;
    const int b   = bid & 127;
    const int mc  = (bid >> 7) & 1;          // m-chunk: p in [mc*112, ...)
    const int nh  = bid >> 8;                // n-half: r in [nh*128, ...)
    const int tid = threadIdx.x;
    const int wave = tid >> 6, lane = tid & 63;
    const int wm = wave >> 2, wn = wave & 3;   // wave grid 2(m) x 4(n)
    const int q  = lane >> 4, ln = lane & 15;
    const int nm = (wm == 0) ? 4 : 3;          // 7 m-tiles split 4 + 3

    f32x4 acc[4][2];
#pragma unroll
    for (int i = 0; i < 4; i++)
#pragma unroll
        for (int j = 0; j < 2; j++) acc[i][j] = (f32x4){0.f, 0.f, 0.f, 0.f};

    // per-lane global srcs (advance by tile stride per kt)
    const __bf16* xa = xt + ((size_t)b * 32 * 196 + (size_t)mc * 112) * 32 + tid * 8;
    const __bf16* wb = w1t + (size_t)nh * 128 * 32 + tid * 8;

    auto issue = [&](int kt, int buf) {
        gload_lds16(xa + (size_t)kt * (196 * 32), &Alds[buf][wave * 512]);
        gload_lds16(wb + (size_t)kt * 8192,       &Blds[buf][wave * 512]);
    };

    issue(0, 0); issue(1, 1); issue(2, 2);     // 6 loads in flight / wave

    for (int t = 0; t < 32; ++t) {
        if (t <= 29)      asm volatile("s_waitcnt vmcnt(4)" ::: "memory");
        else if (t == 30) asm volatile("s_waitcnt vmcnt(2)" ::: "memory");
        else              asm volatile("s_waitcnt vmcnt(0)" ::: "memory");
        __builtin_amdgcn_s_barrier();            // all waves: tile t landed
        __builtin_amdgcn_sched_barrier(0);       // no memory-op hoisting
        if (t + 3 < 32) issue(t + 3, (t + 3) & 3);   // overwrites buf (t-1)&3
        __builtin_amdgcn_sched_barrier(0);       // ds_reads stay below
        const int cur = t & 3;
        bf16x8 bfr[2];
#pragma unroll
        for (int ni = 0; ni < 2; ni++)
            bfr[ni] = *(const bf16x8*)&Blds[cur][(((wn * 2 + ni) * 16 + ln) * 32) + q * 8];
#pragma unroll
        for (int mi = 0; mi < 4; mi++) {
            if (mi < nm) {
                const bf16x8 af =
                    *(const bf16x8*)&Alds[cur][(((wm * 4 + mi) * 16 + ln) * 32) + q * 8];
#pragma unroll
                for (int ni = 0; ni < 2; ni++)
                    acc[mi][ni] = __builtin_amdgcn_mfma_f32_16x16x32_bf16(
                        af, bfr[ni], acc[mi][ni], 0, 0, 0);
            }
        }
    }

    // ---- epilogue: BN + hardswish + partial pool (mask p >= 196) ----
    float psum[2] = {0.f, 0.f};
#pragma unroll
    for (int ni = 0; ni < 2; ni++) {
        const int r = nh * 128 + (wn * 2 + ni) * 16 + ln;
        const float s1 = g1[r] * rsqrtf(v1[r] + EPS_F);
        const float mu = m1[r];
        const float be = b1[r];
#pragma unroll
        for (int mi = 0; mi < 4; mi++) {
            if (mi < nm) {
#pragma unroll
                for (int i = 0; i < 4; i++) {
                    const int m = mc * 112 + (wm * 4 + mi) * 16 + q * 4 + i;
                    if (m < 196) {
                        float v = acc[mi][ni][i];
                        v = (v - mu) * s1 + be;
                        const float g = fminf(fmaxf(v + 3.f, 0.f), 6.f);
                        psum[ni] += v * g * (1.f / 6.f);
                    }
                }
            }
        }
    }
#pragma unroll
    for (int ni = 0; ni < 2; ni++) {
        psum[ni] += __shfl_xor(psum[ni], 16, 64);
        psum[ni] += __shfl_xor(psum[ni], 32, 64);
    }
    if (lane < 16) {
#pragma unroll
        for (int ni = 0; ni < 2; ni++)
            pool_lds[wm][(wn * 2 + ni) * 16 + lane] = psum[ni];
    }
    __syncthreads();
    if (tid < 128)
        pooled_part[(size_t)mc * (128 * 256) + b * 256 + nh * 128 + tid] =
            (pool_lds[0][tid] + pool_lds[1][tid]) * (1.f / 196.f);
}

__device__ __forceinline__ void prep1(float s, float e, int n, int size, int i,
                                      int& lo, int& hi, float& w0, float& w1)
{
    const float bsz = (e - s) / (float)n;
    float c = s + ((float)i + 0.5f) * bsz;
    const float valid = (c >= -1.f && c <= (float)size) ? 1.f : 0.f;
    c = fminf(fmaxf(c, 0.f), (float)(size - 1));
    lo = (int)floorf(c);
    hi = min(lo + 1, size - 1);
    const float f = c - (float)lo;
    w0 = (1.f - f) * valid;
    w1 = f * valid;
}

// -------------------------------------------------------------------------
// Kernel 3 (fused logits+ROI): each block first computes the 6 roi params
// from pooled_part (64 threads, hidden under the x-staging loads), then
// ROI-align as before. grid (128, 32), block 256.
// -------------------------------------------------------------------------
__global__ __launch_bounds__(256) void k_roi(
    const float* __restrict__ x,
    const float* __restrict__ pooled_part,   // [2][128][256]
    const float* __restrict__ w2,
    const float* __restrict__ g2,
    const float* __restrict__ b2,
    const float* __restrict__ m2,
    const float* __restrict__ v2,
    float* __restrict__ out)
{
    __shared__ float xs[32 * 200];   // 32 ch x 196 (pad 200)  25.6 KiB
    __shared__ int   soff[8][80];    // sample flat offsets (po-major)
    __shared__ float swt[8][80];     // sample weights
    __shared__ float roi_s[6];

    const int b = blockIdx.x, c0 = blockIdx.y * 32;
    const int tid = threadIdx.x;

    // ---- stage 32 channels, coalesced float4 (196 = 49*4) ----
    const float* xb = x + ((size_t)b * 1024 + c0) * 196;
#pragma unroll
    for (int k = 0; k < 7; k++) {
        const int i4 = tid + k * 256;
        if (i4 < 1568) {                       // 32*49
            const int c = i4 / 49, pq = i4 % 49;
            const float4 v = *(const float4*)(xb + c * 196 + pq * 4);
            *(float4*)&xs[c * 200 + pq * 4] = v;
        }
    }
    // ---- logits (wave 0), overlapped with staging ----
    if (tid < 64) {
        const float4 pa = ((const float4*)(pooled_part + b * 256))[tid];
        const float4 pb = ((const float4*)(pooled_part + 128 * 256 + b * 256))[tid];
        float4 p4;
        p4.x = pa.x + pb.x; p4.y = pa.y + pb.y;
        p4.z = pa.z + pb.z; p4.w = pa.w + pb.w;
        float part[6];
#pragma unroll
        for (int j = 0; j < 6; j++) {
            const float4 w = *(const float4*)(w2 + j * 256 + tid * 4);
            part[j] = p4.x * w.x + p4.y * w.y + p4.z * w.z + p4.w * w.w;
        }
#pragma unroll
        for (int j = 0; j < 6; j++)
#pragma unroll
            for (int off = 32; off >= 1; off >>= 1)
                part[j] += __shfl_xor(part[j], off, 64);
        if (tid == 0) {
            const float SC[3] = {7.f, 7.f, 4.f};
#pragma unroll
            for (int j = 0; j < 6; j++) {
                float l = part[j];
                const float s = g2[j] * rsqrtf(v2[j] + EPS_F);
                l = (l - m2[j]) * s + b2[j];
                const float raw = 1.f / (1.f + expf(-l));
                roi_s[j] = (j < 3) ? 0.5f * raw * SC[j]
                                   : (1.f - 0.5f * raw) * SC[j - 3];
            }
        }
    }
    __syncthreads();
    // ---- weight/offset tables (75 threads) ----
    if (tid < 75) {
        const int po = tid;
        const int to = po / 25, rem = po % 25, yo = rem / 5, xo = rem % 5;
        int tl, th, yl, yh, xl, xh;
        float tw0, tw1, yw0, yw1, xw0, xw1;
        prep1(roi_s[2], roi_s[5], 3, 4, to, tl, th, tw0, tw1);
        prep1(roi_s[1], roi_s[4], 5, 7, yo, yl, yh, yw0, yw1);
        prep1(roi_s[0], roi_s[3], 5, 7, xo, xl, xh, xw0, xw1);
#pragma unroll
        for (int s = 0; s < 8; s++) {
            const int   ti = (s & 4) ? th : tl;
            const int   yi = (s & 2) ? yh : yl;
            const int   xi = (s & 1) ? xh : xl;
            const float w = ((s & 4) ? tw1 : tw0) *
                            ((s & 2) ? yw1 : yw0) *
                            ((s & 1) ? xw1 : xw0);
            soff[s][po] = ti * 49 + yi * 7 + xi;
            swt[s][po]  = w;
        }
    }
    __syncthreads();

    // ---- compute: 32*75 = 2400 outputs ----
    const size_t obase = ((size_t)b * 1024 + c0) * 75;
#pragma unroll
    for (int k = 0; k < 10; k++) {
        const int e = tid + k * 256;
        if (e < 2400) {
            const int c = e / 75, po = e % 75;
            const float* row = &xs[c * 200];
            float v = 0.f;
#pragma unroll
            for (int s = 0; s < 8; s++)
                v += swt[s][po] * row[soff[s][po]];
            out[obase + e] = v;     // e == c*75+po: fully coalesced
        }
    }
}

extern "C" void kernel_launch(void* const* d_in, const int* in_sizes, int n_in,
                              void* d_out, int out_size, void* d_ws, size_t ws_size,
                              hipStream_t stream)
{
    const float* x  = (const float*)d_in[0];
    const float* w1 = (const float*)d_in[1];
    const float* g1 = (const float*)d_in[2];
    const float* b1 = (const float*)d_in[3];
    const float* m1 = (const float*)d_in[4];
    const float* v1 = (const float*)d_in[5];
    const float* w2 = (const float*)d_in[6];
    const float* g2 = (const float*)d_in[7];
    const float* b2 = (const float*)d_in[8];
    const float* m2 = (const float*)d_in[9];
    const float* v2 = (const float*)d_in[10];

    // workspace layout (bytes):
    //   xt   : 128*32*196*32*2 = 51,380,224  (+8192 OOB pad for last-tile DMA)
    //   w1t  : 32*256*32*2     =    524,288
    //   pooled_part : 2*128*256*4 = 262,144
    char* wsb = (char*)d_ws;
    __bf16* xt     = (__bf16*)wsb;
    __bf16* w1t    = (__bf16*)(wsb + 51388416);
    float*  pooled = (float*)(wsb + 51912704);
    float*  out    = (float*)d_out;

    k_pack<<<dim3(129, 32), 256, 0, stream>>>(x, w1, xt, w1t);
    k_gemm_pool<<<512, 512, 0, stream>>>(xt, w1t, g1, b1, m1, v1, pooled);
    k_roi<<<dim3(128, 32), 256, 0, stream>>>(x, pooled, w2, g2, b2, m2, v2, out);
}